// Round 3
// baseline (17014.861 us; speedup 1.0000x reference)
//
#include <hip/hip_runtime.h>

// 2-layer bidirectional GRU (T=512,B=32,I=H=O=512) + FC, bf16 MFMA compute.
//
// Round 3: tagged-word h-exchange. Each exchanged h value is a u32
// {step_tag:16, bf16(h):16}, double-buffered by step parity:
//   hx[parity][dir][b][j], producer at step s writes tag s+1 into parity
//   (s+1)&1; consumer at step s stages parity s&1 and requires every word's
//   tag == s. 32-bit stores are atomic, so tag validity implies data
//   validity with NO producer-side vmcnt drain, NO atomics, NO flags.
//   Overwrite-safe: parity p is next overwritten at tag s+2, which requires
//   all same-dir waves published s+1, which requires they finished reading
//   tag s. Per-word equality (==s) makes stale cross-replay tags fail closed.
//
// GRU recurrence: 16 WGs x 256 thr. Wave w: dir=w>>1 (0 fwd,1 bwd), p=w&1.
// Wave owns hidden slice j0=[wg*32+p*16, +16). W_hh fragments (192 VGPR/lane)
// persist in registers for all 512 steps; h carried in f32 regs.

typedef unsigned short u16;
typedef __attribute__((ext_vector_type(8))) short bf16x8;
typedef __attribute__((ext_vector_type(4))) float f32x4;

__device__ __forceinline__ u16 f2bf(float f) {
  unsigned u = __float_as_uint(f);
  u += 0x7fffu + ((u >> 16) & 1u);
  return (u16)(u >> 16);
}
__device__ __forceinline__ float bf2f(u16 v) {
  return __uint_as_float((unsigned)v << 16);
}

template<int AUX>
__device__ __forceinline__ void gl_lds16(const void* g, void* l) {
  __builtin_amdgcn_global_load_lds((const __attribute__((address_space(1))) void*)g,
                                   (__attribute__((address_space(3))) void*)l, 16, 0, AUX);
}

__device__ __forceinline__ void st_u32_cc(unsigned* p, unsigned v) {
  asm volatile("global_store_dword %0, %1, off sc0 sc1" :: "v"(p), "v"(v) : "memory");
}

// ---------------- utility kernels ----------------

__global__ void k_cvt(const float* __restrict__ s, u16* __restrict__ d, int n) {
  int i = (blockIdx.x * blockDim.x + threadIdx.x) * 4;
  if (i < n) {
    float4 v = *(const float4*)(s + i);
    unsigned a = (unsigned)f2bf(v.x) | ((unsigned)f2bf(v.y) << 16);
    unsigned b = (unsigned)f2bf(v.z) | ((unsigned)f2bf(v.w) << 16);
    uint2 o; o.x = a; o.y = b;
    *(uint2*)(d + i) = o;
  }
}

__global__ void k_copyf(const float* __restrict__ s, float* __restrict__ d, int n) {
  int i = blockIdx.x * blockDim.x + threadIdx.x;
  if (i < n) d[i] = s[i];
}

// pack h0 (f32 [4][32][512]) into tagged exchange buffers: parity0 = {tag0,h},
// parity1 = invalid marker. hx layout: [parity][dir][b][j], 32768 u32/parity.
__global__ void k_hpack(const float* __restrict__ h,
                        unsigned* __restrict__ hx0, unsigned* __restrict__ hx1) {
  int i = blockIdx.x * blockDim.x + threadIdx.x;
  if (i < 65536) {
    int layer = i >> 15, r = i & 32767;
    unsigned* hx = layer ? hx1 : hx0;
    hx[r] = (unsigned)f2bf(h[(size_t)layer * 32768 + r]);  // tag 0
    hx[32768 + r] = 0xFFFF0000u;                           // never matches
  }
}

// ------- tiled bf16 MFMA GEMM:  C[M,N] = A[M,K] * B[N,K]^T + bias -------

template<bool BF16OUT>
__global__ __launch_bounds__(256) void k_gemm(
    const u16* __restrict__ A, const u16* __restrict__ B,
    const float* __restrict__ bias, void* __restrict__ Cv,
    int N, int K)
{
  __shared__ u16 As[128 * 32];
  __shared__ u16 Bs[128 * 32];
  const int tid = threadIdx.x;
  const int w = tid >> 6, l = tid & 63;
  const int bm = blockIdx.x, bn = blockIdx.y;
  const int lj = l & 15, lk = l >> 4;
  const int wm = (w & 1) * 64, wn = (w >> 1) * 64;
  const int srow = l >> 2, scol = (l & 3) * 8;
  f32x4 acc[4][4] = {};
  const u16* Ab = A + (size_t)bm * 128 * K;
  const u16* Bb = B + (size_t)bn * 128 * K;

  for (int kt = 0; kt < K; kt += 32) {
#pragma unroll
    for (int i = 0; i < 2; ++i) {
      int r0 = i * 64 + w * 16;
      gl_lds16<0>(Ab + (size_t)(r0 + srow) * K + kt + scol, &As[r0 * 32]);
      gl_lds16<0>(Bb + (size_t)(r0 + srow) * K + kt + scol, &Bs[r0 * 32]);
    }
    __syncthreads();
    bf16x8 af[4], bf[4];
#pragma unroll
    for (int i = 0; i < 4; ++i) af[i] = *(const bf16x8*)&As[(wm + i * 16 + lj) * 32 + lk * 8];
#pragma unroll
    for (int j = 0; j < 4; ++j) bf[j] = *(const bf16x8*)&Bs[(wn + j * 16 + lj) * 32 + lk * 8];
#pragma unroll
    for (int i = 0; i < 4; ++i)
#pragma unroll
      for (int j = 0; j < 4; ++j)
        acc[i][j] = __builtin_amdgcn_mfma_f32_16x16x32_bf16(af[i], bf[j], acc[i][j], 0, 0, 0);
    __syncthreads();
  }

#pragma unroll
  for (int i = 0; i < 4; ++i)
#pragma unroll
    for (int j = 0; j < 4; ++j) {
      int col = bn * 128 + wn + j * 16 + lj;
      float bv = bias[col];
#pragma unroll
      for (int r2 = 0; r2 < 4; ++r2) {
        int row = bm * 128 + wm + i * 16 + lk * 4 + r2;
        float v = acc[i][j][r2] + bv;
        if (BF16OUT) ((u16*)Cv)[(size_t)row * N + col] = f2bf(v);
        else         ((float*)Cv)[(size_t)row * N + col] = v;
      }
    }
}

// ---------------- persistent GRU layer (both directions) ----------------

#define USTR 516  // LDS row stride in u32 (2048B + 16B pad; keeps b128 16B-aligned)

__global__ __launch_bounds__(256, 1) void k_gru(
    const u16*  __restrict__ gi,      // [512*32][3072] bf16; fwd 0:1536, bwd 1536:3072
    const float* __restrict__ whhf,   // [1536][512]
    const float* __restrict__ whhb,
    const float* __restrict__ bhhf,   // [1536]
    const float* __restrict__ bhhb,
    const float* __restrict__ h0,     // this layer: [2][32][512] f32
    unsigned* __restrict__ hx,        // [2 parity][2 dir][32][512] u32 tagged
    u16* __restrict__ y,              // [512][32][1024] bf16 (plain, next layer)
    float* __restrict__ hn)           // this layer: [2][32][512] f32 (d_out)
{
  __shared__ unsigned hl[2][32 * USTR];   // 132096 B
  __shared__ int sh_need[2];
  const int tid = threadIdx.x, wg = blockIdx.x;
  const int w = tid >> 6, l = tid & 63;
  const int dir = w >> 1, p = w & 1;
  const int j0 = wg * 32 + p * 16;
  const int lj = l & 15, lk = l >> 4;
  const float* whh = dir ? whhb : whhf;
  const float* bhh = dir ? bhhb : bhhf;

  // persistent W_hh fragments: [gate r/z/n][k-chunk]
  bf16x8 bfr[3][16];
#pragma unroll
  for (int g = 0; g < 3; ++g) {
    const float* wr = whh + (size_t)(g * 512 + j0 + lj) * 512;
#pragma unroll
    for (int kc = 0; kc < 16; ++kc) {
      const float* s4 = wr + kc * 32 + lk * 8;
      float4 a = *(const float4*)s4;
      float4 b = *(const float4*)(s4 + 4);
      bf16x8 v;
      v[0] = (short)f2bf(a.x); v[1] = (short)f2bf(a.y); v[2] = (short)f2bf(a.z); v[3] = (short)f2bf(a.w);
      v[4] = (short)f2bf(b.x); v[5] = (short)f2bf(b.y); v[6] = (short)f2bf(b.z); v[7] = (short)f2bf(b.w);
      bfr[g][kc] = v;
    }
  }
  float bb[3];
#pragma unroll
  for (int g = 0; g < 3; ++g) bb[g] = bhh[g * 512 + j0 + lj];

  float hreg[2][4];
#pragma unroll
  for (int mt = 0; mt < 2; ++mt)
#pragma unroll
    for (int i = 0; i < 4; ++i)
      hreg[mt][i] = h0[((size_t)dir * 32 + (mt * 16 + lk * 4 + i)) * 512 + j0 + lj];

  for (int s = 0; s < 512; ++s) {
    const int tq = dir ? (511 - s) : s;

    // prefetch input-gate values (plain loads; overlap the exchange latency)
    float gg[2][4][3];
#pragma unroll
    for (int mt = 0; mt < 2; ++mt)
#pragma unroll
      for (int i = 0; i < 4; ++i) {
        int b = mt * 16 + lk * 4 + i;
        const u16* gp = gi + ((size_t)tq * 32 + b) * 3072 + dir * 1536 + j0 + lj;
        gg[mt][i][0] = bf2f(gp[0]);
        gg[mt][i][1] = bf2f(gp[512]);
        gg[mt][i][2] = bf2f(gp[1024]);
      }

    if (tid < 2) sh_need[tid] = 1;
    __syncthreads();

    const unsigned exp = (unsigned)s;
    const unsigned* hsrc = hx + (size_t)(s & 1) * 32768 + dir * 16384;
    f32x4 acc[2][3];
    int attempts = 0;

    for (;;) {
      // stage my dir's tagged words (LLC-coherent) into LDS, 16 rows/wave
      if (sh_need[dir]) {
#pragma unroll
        for (int r = 0; r < 16; ++r) {
          int row = p * 16 + r;
#pragma unroll
          for (int hf = 0; hf < 2; ++hf)
            gl_lds16<17>(hsrc + (size_t)row * 512 + hf * 256 + l * 4,
                         &hl[dir][row * USTR + hf * 256]);
        }
      }
      __syncthreads();                       // (A) drains gl_lds

      bool bad = false;
      if (sh_need[dir]) {
#pragma unroll
        for (int mt = 0; mt < 2; ++mt)
#pragma unroll
          for (int g = 0; g < 3; ++g)
            acc[mt][g] = (f32x4){bb[g], bb[g], bb[g], bb[g]};
        unsigned ok = 1u;
#pragma unroll
        for (int kc = 0; kc < 16; ++kc) {
#pragma unroll
          for (int mt = 0; mt < 2; ++mt) {
            const unsigned* hp = &hl[dir][(mt * 16 + lj) * USTR + kc * 32 + lk * 8];
            uint4 wa = *(const uint4*)hp;
            uint4 wb = *(const uint4*)(hp + 4);
            ok &= (unsigned)((wa.x >> 16) == exp); ok &= (unsigned)((wa.y >> 16) == exp);
            ok &= (unsigned)((wa.z >> 16) == exp); ok &= (unsigned)((wa.w >> 16) == exp);
            ok &= (unsigned)((wb.x >> 16) == exp); ok &= (unsigned)((wb.y >> 16) == exp);
            ok &= (unsigned)((wb.z >> 16) == exp); ok &= (unsigned)((wb.w >> 16) == exp);
            union { unsigned u[4]; bf16x8 v; } f;
            f.u[0] = (wa.x & 0xffffu) | (wa.y << 16);
            f.u[1] = (wa.z & 0xffffu) | (wa.w << 16);
            f.u[2] = (wb.x & 0xffffu) | (wb.y << 16);
            f.u[3] = (wb.z & 0xffffu) | (wb.w << 16);
#pragma unroll
            for (int g = 0; g < 3; ++g)
              acc[mt][g] = __builtin_amdgcn_mfma_f32_16x16x32_bf16(f.v, bfr[g][kc], acc[mt][g], 0, 0, 0);
          }
        }
        bad = !__all((int)ok);               // wave-uniform verdict
      }
      __syncthreads();                       // (B) checks done
      if (tid < 2) sh_need[tid] = 0;
      __syncthreads();                       // (C) clear visible
      if (bad && l == 0) sh_need[dir] = 1;   // vote (same-value multi-write)
      __syncthreads();                       // (D) votes visible
      if (!(sh_need[0] | sh_need[1])) break;
      if (++attempts > 32768) break;         // safety: terminates, never hangs
    }

    // epilogue: gates + h update + tagged publish + plain y store
    const unsigned wtag = (unsigned)(s + 1) << 16;
    unsigned* hdst = hx + (size_t)((s + 1) & 1) * 32768 + dir * 16384;
#pragma unroll
    for (int mt = 0; mt < 2; ++mt)
#pragma unroll
      for (int i = 0; i < 4; ++i) {
        int b = mt * 16 + lk * 4 + i;
        float r = 1.f / (1.f + __expf(-(gg[mt][i][0] + acc[mt][0][i])));
        float z = 1.f / (1.f + __expf(-(gg[mt][i][1] + acc[mt][1][i])));
        float nx = gg[mt][i][2] + r * acc[mt][2][i];
        float n = 1.f - 2.f / (1.f + __expf(2.f * nx));
        float h = (1.f - z) * n + z * hreg[mt][i];
        hreg[mt][i] = h;
        u16 hb = f2bf(h);
        st_u32_cc(&hdst[(size_t)b * 512 + j0 + lj], wtag | (unsigned)hb);
        y[((size_t)tq * 32 + b) * 1024 + dir * 512 + j0 + lj] = hb;
        if (s == 511) hn[((size_t)dir * 32 + b) * 512 + j0 + lj] = h;
      }
  }
}

// ---------------- host ----------------

extern "C" void kernel_launch(void* const* d_in, const int* in_sizes, int n_in,
                              void* d_out, int out_size, void* d_ws, size_t ws_size,
                              hipStream_t stream)
{
  const float* x     = (const float*)d_in[0];
  const float* h     = (const float*)d_in[1];
  const float* wih0f = (const float*)d_in[2];
  const float* whh0f = (const float*)d_in[3];
  const float* bih0f = (const float*)d_in[4];
  const float* bhh0f = (const float*)d_in[5];
  const float* wih0b = (const float*)d_in[6];
  const float* whh0b = (const float*)d_in[7];
  const float* bih0b = (const float*)d_in[8];
  const float* bhh0b = (const float*)d_in[9];
  const float* wih1f = (const float*)d_in[10];
  const float* whh1f = (const float*)d_in[11];
  const float* bih1f = (const float*)d_in[12];
  const float* bhh1f = (const float*)d_in[13];
  const float* wih1b = (const float*)d_in[14];
  const float* whh1b = (const float*)d_in[15];
  const float* bih1b = (const float*)d_in[16];
  const float* bhh1b = (const float*)d_in[17];
  const float* fcw   = (const float*)d_in[18];
  const float* fcb   = (const float*)d_in[19];
  (void)in_sizes; (void)n_in; (void)out_size;

  char* ws = (char*)d_ws;
  size_t off = 0;
  auto alloc = [&](size_t bytes) { void* p = ws + off; off += (bytes + 255) & ~(size_t)255; return p; };
  u16*      gi    = (u16*)     alloc(16384ull * 3072 * 2);   // 100.7 MB
  u16*      y0    = (u16*)     alloc(16384ull * 1024 * 2);   // 33.6 MB
  char*     y1r   = (char*)    alloc(16384ull * 1024 * 2);   // 33.6 MB (aliased below)
  u16*      Wfc   = (u16*)     alloc(512ull * 1024 * 2);
  unsigned* hx0   = (unsigned*)alloc(65536ull * 4);          // 256 KB tagged exchange L0
  unsigned* hx1   = (unsigned*)alloc(65536ull * 4);          // 256 KB tagged exchange L1
  float*    bias0 = (float*)   alloc(3072 * 4);
  float*    bias1 = (float*)   alloc(3072 * 4);
  size_t need = off;

  if (ws_size < need) {  // diagnosable failure instead of a page fault
    hipMemsetAsync(d_out, 0, (size_t)out_size * sizeof(float), stream);
    return;
  }

  // xb / Wih0 / Wih1 die after GEMM1; y1 written only after that -> alias.
  u16* y1   = (u16*)y1r;
  u16* xb   = (u16*)y1r;
  u16* Wih0 = (u16*)(y1r + 16777216);
  u16* Wih1 = (u16*)(y1r + 16777216 + 3145728);

  float* out = (float*)d_out;
  float* hn  = out + 512ull * 32 * 512;

  auto cvt = [&](const float* s, u16* d, int n) {
    k_cvt<<<dim3((n / 4 + 255) / 256), 256, 0, stream>>>(s, d, n);
  };
  cvt(x, xb, 16384 * 512);
  cvt(wih0f, Wih0, 1536 * 512);
  cvt(wih0b, Wih0 + 1536 * 512, 1536 * 512);
  cvt(wih1f, Wih1, 1536 * 1024);
  cvt(wih1b, Wih1 + 1536 * 1024, 1536 * 1024);
  cvt(fcw, Wfc, 512 * 1024);
  k_hpack<<<256, 256, 0, stream>>>(h, hx0, hx1);
  k_copyf<<<6, 256, 0, stream>>>(bih0f, bias0, 1536);
  k_copyf<<<6, 256, 0, stream>>>(bih0b, bias0 + 1536, 1536);
  k_copyf<<<6, 256, 0, stream>>>(bih1f, bias1, 1536);
  k_copyf<<<6, 256, 0, stream>>>(bih1b, bias1 + 1536, 1536);

  // layer 0
  k_gemm<true><<<dim3(128, 24), 256, 0, stream>>>(xb, Wih0, bias0, gi, 3072, 512);
  k_gru<<<16, 256, 0, stream>>>(gi, whh0f, whh0b, bhh0f, bhh0b,
                                h, hx0, y0, hn);
  // layer 1
  k_gemm<true><<<dim3(128, 24), 256, 0, stream>>>(y0, Wih1, bias1, gi, 3072, 1024);
  k_gru<<<16, 256, 0, stream>>>(gi, whh1f, whh1b, bhh1f, bhh1b,
                                h + 2 * 32 * 512, hx1,
                                y1, hn + 2ull * 32 * 512);
  // FC
  k_gemm<false><<<dim3(128, 4), 256, 0, stream>>>(y1, Wfc, fcb, out, 512, 1024);
}

// Round 4
// 9648.188 us; speedup vs baseline: 1.7635x; 1.7635x over previous
//
#include <hip/hip_runtime.h>

// 2-layer bidirectional GRU (T=512,B=32,I=H=O=512) + FC, bf16 MFMA compute.
//
// Round 4: round-2 flag-then-stage structure, with store-only parallel flags.
//   - 8 persistent WGs x 512 thr per GRU layer. Wave w: dir=w>>2, p=w&3,
//     hidden slice j0 = wg*64 + p*16.
//   - Per step: producers store h (bf16, sc0 sc1) into y[t], drain vmcnt(0),
//     block barrier, then tid0 STORES flags[wg]=s+1 (no atomic RMW fan-in).
//     Consumers tight-poll 8 flag words (lanes l&7, __all(v>=s)), then stage
//     the full 32x512 h of their dir into LDS via global_load_lds sc0sc1.
//   - Max inter-WG skew = 1 step (poll at s requires all >= s), y rows are
//     per-timestep distinct => no overwrite hazard, no parity buffers.
//   - W_hh fragments (192 VGPR/lane) persist in registers all 512 steps;
//     h carried in f32 regs (same lane owns same (b,j) forever).

typedef unsigned short u16;
typedef __attribute__((ext_vector_type(8))) short bf16x8;
typedef __attribute__((ext_vector_type(4))) float f32x4;

__device__ __forceinline__ u16 f2bf(float f) {
  unsigned u = __float_as_uint(f);
  u += 0x7fffu + ((u >> 16) & 1u);
  return (u16)(u >> 16);
}
__device__ __forceinline__ float bf2f(u16 v) {
  return __uint_as_float((unsigned)v << 16);
}

template<int AUX>
__device__ __forceinline__ void gl_lds16(const void* g, void* l) {
  __builtin_amdgcn_global_load_lds((const __attribute__((address_space(1))) void*)g,
                                   (__attribute__((address_space(3))) void*)l, 16, 0, AUX);
}

__device__ __forceinline__ void st_bf16_cc(u16* p, u16 v) {
  unsigned vv = v;
  asm volatile("global_store_short %0, %1, off sc0 sc1" :: "v"(p), "v"(vv) : "memory");
}
__device__ __forceinline__ void st_u32_cc(unsigned* p, unsigned v) {
  asm volatile("global_store_dword %0, %1, off sc0 sc1" :: "v"(p), "v"(v) : "memory");
}

// ---------------- utility kernels ----------------

__global__ void k_zero(unsigned* p, int n) {
  int i = blockIdx.x * blockDim.x + threadIdx.x;
  if (i < n) p[i] = 0u;
}

__global__ void k_cvt(const float* __restrict__ s, u16* __restrict__ d, int n) {
  int i = (blockIdx.x * blockDim.x + threadIdx.x) * 4;
  if (i < n) {
    float4 v = *(const float4*)(s + i);
    unsigned a = (unsigned)f2bf(v.x) | ((unsigned)f2bf(v.y) << 16);
    unsigned b = (unsigned)f2bf(v.z) | ((unsigned)f2bf(v.w) << 16);
    uint2 o; o.x = a; o.y = b;
    *(uint2*)(d + i) = o;
  }
}

__global__ void k_copyf(const float* __restrict__ s, float* __restrict__ d, int n) {
  int i = blockIdx.x * blockDim.x + threadIdx.x;
  if (i < n) d[i] = s[i];
}

// ------- tiled bf16 MFMA GEMM:  C[M,N] = A[M,K] * B[N,K]^T + bias -------

template<bool BF16OUT>
__global__ __launch_bounds__(256) void k_gemm(
    const u16* __restrict__ A, const u16* __restrict__ B,
    const float* __restrict__ bias, void* __restrict__ Cv,
    int N, int K)
{
  __shared__ u16 As[128 * 32];
  __shared__ u16 Bs[128 * 32];
  const int tid = threadIdx.x;
  const int w = tid >> 6, l = tid & 63;
  const int bm = blockIdx.x, bn = blockIdx.y;
  const int lj = l & 15, lk = l >> 4;
  const int wm = (w & 1) * 64, wn = (w >> 1) * 64;
  const int srow = l >> 2, scol = (l & 3) * 8;
  f32x4 acc[4][4] = {};
  const u16* Ab = A + (size_t)bm * 128 * K;
  const u16* Bb = B + (size_t)bn * 128 * K;

  for (int kt = 0; kt < K; kt += 32) {
#pragma unroll
    for (int i = 0; i < 2; ++i) {
      int r0 = i * 64 + w * 16;
      gl_lds16<0>(Ab + (size_t)(r0 + srow) * K + kt + scol, &As[r0 * 32]);
      gl_lds16<0>(Bb + (size_t)(r0 + srow) * K + kt + scol, &Bs[r0 * 32]);
    }
    __syncthreads();
    bf16x8 af[4], bf[4];
#pragma unroll
    for (int i = 0; i < 4; ++i) af[i] = *(const bf16x8*)&As[(wm + i * 16 + lj) * 32 + lk * 8];
#pragma unroll
    for (int j = 0; j < 4; ++j) bf[j] = *(const bf16x8*)&Bs[(wn + j * 16 + lj) * 32 + lk * 8];
#pragma unroll
    for (int i = 0; i < 4; ++i)
#pragma unroll
      for (int j = 0; j < 4; ++j)
        acc[i][j] = __builtin_amdgcn_mfma_f32_16x16x32_bf16(af[i], bf[j], acc[i][j], 0, 0, 0);
    __syncthreads();
  }

#pragma unroll
  for (int i = 0; i < 4; ++i)
#pragma unroll
    for (int j = 0; j < 4; ++j) {
      int col = bn * 128 + wn + j * 16 + lj;
      float bv = bias[col];
#pragma unroll
      for (int r2 = 0; r2 < 4; ++r2) {
        int row = bm * 128 + wm + i * 16 + lk * 4 + r2;
        float v = acc[i][j][r2] + bv;
        if (BF16OUT) ((u16*)Cv)[(size_t)row * N + col] = f2bf(v);
        else         ((float*)Cv)[(size_t)row * N + col] = v;
      }
    }
}

// ---------------- persistent GRU layer (both directions) ----------------

#define LSTR 536  // padded LDS row stride in bf16 elems (1072 B, 16B-aligned)

__global__ __launch_bounds__(512, 2) void k_gru(
    const u16*  __restrict__ gi,      // [512*32][3072] bf16; fwd 0:1536, bwd 1536:3072
    const float* __restrict__ whhf,   // [1536][512]
    const float* __restrict__ whhb,
    const float* __restrict__ bhhf,   // [1536]
    const float* __restrict__ bhhb,
    const float* __restrict__ h0,     // this layer: [2][32][512] f32
    const u16*  __restrict__ hinit,   // this layer: [2][32][512] bf16
    u16* __restrict__ y,              // [512][32][1024] bf16 (exchange + next layer)
    float* __restrict__ hn,           // this layer: [2][32][512] f32 (d_out)
    unsigned* __restrict__ flags)     // this layer: [8] tag words (=s+1 after step s)
{
  __shared__ u16 hl[2][32 * LSTR];    // 68.6 KB
  const int tid = threadIdx.x, wg = blockIdx.x;
  const int w = tid >> 6, l = tid & 63;
  const int dir = w >> 3 ? 1 : (w >> 2);     // w in 0..7: dir = w>>2
  const int p = w & 3;
  const int j0 = wg * 64 + p * 16;
  const int lj = l & 15, lk = l >> 4;
  const float* whh = dir ? whhb : whhf;
  const float* bhh = dir ? bhhb : bhhf;

  // persistent W_hh fragments: [gate r/z/n][k-chunk]
  bf16x8 bfr[3][16];
#pragma unroll
  for (int g = 0; g < 3; ++g) {
    const float* wr = whh + (size_t)(g * 512 + j0 + lj) * 512;
#pragma unroll
    for (int kc = 0; kc < 16; ++kc) {
      const float* s4 = wr + kc * 32 + lk * 8;
      float4 a = *(const float4*)s4;
      float4 b = *(const float4*)(s4 + 4);
      bf16x8 v;
      v[0] = (short)f2bf(a.x); v[1] = (short)f2bf(a.y); v[2] = (short)f2bf(a.z); v[3] = (short)f2bf(a.w);
      v[4] = (short)f2bf(b.x); v[5] = (short)f2bf(b.y); v[6] = (short)f2bf(b.z); v[7] = (short)f2bf(b.w);
      bfr[g][kc] = v;
    }
  }
  float bb[3];
#pragma unroll
  for (int g = 0; g < 3; ++g) bb[g] = bhh[g * 512 + j0 + lj];

  float hreg[2][4];
#pragma unroll
  for (int mt = 0; mt < 2; ++mt)
#pragma unroll
    for (int i = 0; i < 4; ++i)
      hreg[mt][i] = h0[((size_t)dir * 32 + (mt * 16 + lk * 4 + i)) * 512 + j0 + lj];

  for (int s = 0; s < 512; ++s) {
    const int tq = dir ? (511 - s) : s;

    // prefetch input-gate values (plain loads; in flight during the flag wait)
    float gg[2][4][3];
#pragma unroll
    for (int mt = 0; mt < 2; ++mt)
#pragma unroll
      for (int i = 0; i < 4; ++i) {
        int b = mt * 16 + lk * 4 + i;
        const u16* gp = gi + ((size_t)tq * 32 + b) * 3072 + dir * 1536 + j0 + lj;
        gg[mt][i][0] = bf2f(gp[0]);
        gg[mt][i][1] = bf2f(gp[512]);
        gg[mt][i][2] = bf2f(gp[1024]);
      }

    if (s > 0) {
      const unsigned ss = (unsigned)s;
      unsigned cap = 0;
      for (;;) {
        unsigned v = __hip_atomic_load(&flags[l & 7], __ATOMIC_RELAXED,
                                       __HIP_MEMORY_SCOPE_AGENT);
        if (__all((int)(v >= ss))) break;
        if (++cap > (1u << 20)) break;  // safety: terminates, never hangs
      }
    }

    // stage h_prev of my dir into LDS: 4 waves/dir x 8 rows each (1 KB/row)
    {
      const u16* src; int rstride, cbase;
      if (s == 0) { src = hinit + (size_t)dir * 32 * 512; rstride = 512; cbase = 0; }
      else { int tp = dir ? (tq + 1) : (tq - 1); src = y + (size_t)tp * 32 * 1024; rstride = 1024; cbase = dir * 512; }
#pragma unroll
      for (int r = 0; r < 8; ++r) {
        int row = p * 8 + r;
        gl_lds16<17>(src + (size_t)row * rstride + cbase + l * 8, &hl[dir][row * LSTR]);
      }
    }
    __syncthreads();                      // gl_lds drained, LDS visible

    f32x4 acc[2][3];
#pragma unroll
    for (int mt = 0; mt < 2; ++mt)
#pragma unroll
      for (int g = 0; g < 3; ++g)
        acc[mt][g] = (f32x4){bb[g], bb[g], bb[g], bb[g]};

#pragma unroll
    for (int kc = 0; kc < 16; ++kc) {
      bf16x8 a0 = *(const bf16x8*)&hl[dir][lj * LSTR + kc * 32 + lk * 8];
      bf16x8 a1 = *(const bf16x8*)&hl[dir][(16 + lj) * LSTR + kc * 32 + lk * 8];
#pragma unroll
      for (int g = 0; g < 3; ++g) {
        acc[0][g] = __builtin_amdgcn_mfma_f32_16x16x32_bf16(a0, bfr[g][kc], acc[0][g], 0, 0, 0);
        acc[1][g] = __builtin_amdgcn_mfma_f32_16x16x32_bf16(a1, bfr[g][kc], acc[1][g], 0, 0, 0);
      }
    }
    __syncthreads();                      // protect LDS before next step's staging

    // epilogue: gates + h update + coherent y store
#pragma unroll
    for (int mt = 0; mt < 2; ++mt)
#pragma unroll
      for (int i = 0; i < 4; ++i) {
        int b = mt * 16 + lk * 4 + i;
        float r = 1.f / (1.f + __expf(-(gg[mt][i][0] + acc[mt][0][i])));
        float z = 1.f / (1.f + __expf(-(gg[mt][i][1] + acc[mt][1][i])));
        float nx = gg[mt][i][2] + r * acc[mt][2][i];
        float n = 1.f - 2.f / (1.f + __expf(2.f * nx));
        float h = (1.f - z) * n + z * hreg[mt][i];
        hreg[mt][i] = h;
        st_bf16_cc(y + ((size_t)tq * 32 + b) * 1024 + dir * 512 + j0 + lj, f2bf(h));
        if (s == 511) hn[((size_t)dir * 32 + b) * 512 + j0 + lj] = h;
      }

    asm volatile("s_waitcnt vmcnt(0)" ::: "memory");  // my stores at coherence point
    __syncthreads();                      // all 8 waves' stores drained
    if (tid == 0) st_u32_cc(&flags[wg], (unsigned)(s + 1));  // parallel publish
  }
}

// ---------------- host ----------------

extern "C" void kernel_launch(void* const* d_in, const int* in_sizes, int n_in,
                              void* d_out, int out_size, void* d_ws, size_t ws_size,
                              hipStream_t stream)
{
  const float* x     = (const float*)d_in[0];
  const float* h     = (const float*)d_in[1];
  const float* wih0f = (const float*)d_in[2];
  const float* whh0f = (const float*)d_in[3];
  const float* bih0f = (const float*)d_in[4];
  const float* bhh0f = (const float*)d_in[5];
  const float* wih0b = (const float*)d_in[6];
  const float* whh0b = (const float*)d_in[7];
  const float* bih0b = (const float*)d_in[8];
  const float* bhh0b = (const float*)d_in[9];
  const float* wih1f = (const float*)d_in[10];
  const float* whh1f = (const float*)d_in[11];
  const float* bih1f = (const float*)d_in[12];
  const float* bhh1f = (const float*)d_in[13];
  const float* wih1b = (const float*)d_in[14];
  const float* whh1b = (const float*)d_in[15];
  const float* bih1b = (const float*)d_in[16];
  const float* bhh1b = (const float*)d_in[17];
  const float* fcw   = (const float*)d_in[18];
  const float* fcb   = (const float*)d_in[19];
  (void)in_sizes; (void)n_in; (void)out_size;

  char* ws = (char*)d_ws;
  size_t off = 0;
  auto alloc = [&](size_t bytes) { void* p = ws + off; off += (bytes + 255) & ~(size_t)255; return p; };
  u16*      gi    = (u16*)     alloc(16384ull * 3072 * 2);   // 100.7 MB
  u16*      y0    = (u16*)     alloc(16384ull * 1024 * 2);   // 33.6 MB
  char*     y1r   = (char*)    alloc(16384ull * 1024 * 2);   // 33.6 MB (aliased below)
  u16*      Wfc   = (u16*)     alloc(512ull * 1024 * 2);
  u16*      hinit = (u16*)     alloc(4ull * 32 * 512 * 2);
  float*    bias0 = (float*)   alloc(3072 * 4);
  float*    bias1 = (float*)   alloc(3072 * 4);
  unsigned* flags = (unsigned*)alloc(16 * 4);                // 8 per layer
  size_t need = off;

  if (ws_size < need) {  // diagnosable failure instead of a page fault
    hipMemsetAsync(d_out, 0, (size_t)out_size * sizeof(float), stream);
    return;
  }

  // xb / Wih0 / Wih1 die after GEMM1; y1 written only after that -> alias.
  u16* y1   = (u16*)y1r;
  u16* xb   = (u16*)y1r;
  u16* Wih0 = (u16*)(y1r + 16777216);
  u16* Wih1 = (u16*)(y1r + 16777216 + 3145728);

  float* out = (float*)d_out;
  float* hn  = out + 512ull * 32 * 512;

  k_zero<<<1, 64, 0, stream>>>(flags, 16);
  auto cvt = [&](const float* s, u16* d, int n) {
    k_cvt<<<dim3((n / 4 + 255) / 256), 256, 0, stream>>>(s, d, n);
  };
  cvt(x, xb, 16384 * 512);
  cvt(wih0f, Wih0, 1536 * 512);
  cvt(wih0b, Wih0 + 1536 * 512, 1536 * 512);
  cvt(wih1f, Wih1, 1536 * 1024);
  cvt(wih1b, Wih1 + 1536 * 1024, 1536 * 1024);
  cvt(fcw, Wfc, 512 * 1024);
  cvt(h, hinit, 4 * 32 * 512);
  k_copyf<<<6, 256, 0, stream>>>(bih0f, bias0, 1536);
  k_copyf<<<6, 256, 0, stream>>>(bih0b, bias0 + 1536, 1536);
  k_copyf<<<6, 256, 0, stream>>>(bih1f, bias1, 1536);
  k_copyf<<<6, 256, 0, stream>>>(bih1b, bias1 + 1536, 1536);

  // layer 0
  k_gemm<true><<<dim3(128, 24), 256, 0, stream>>>(xb, Wih0, bias0, gi, 3072, 512);
  k_gru<<<8, 512, 0, stream>>>(gi, whh0f, whh0b, bhh0f, bhh0b,
                               h, hinit, y0, hn, flags);
  // layer 1
  k_gemm<true><<<dim3(128, 24), 256, 0, stream>>>(y0, Wih1, bias1, gi, 3072, 1024);
  k_gru<<<8, 512, 0, stream>>>(gi, whh1f, whh1b, bhh1f, bhh1b,
                               h + 2 * 32 * 512, hinit + 2 * 32 * 512,
                               y1, hn + 2ull * 32 * 512, flags + 8);
  // FC
  k_gemm<false><<<dim3(128, 4), 256, 0, stream>>>(y1, Wfc, fcb, out, 512, 1024);
}

// Round 5
// 4843.904 us; speedup vs baseline: 3.5126x; 1.9918x over previous
//
#include <hip/hip_runtime.h>

// 2-layer bidirectional GRU (T=512,B=32,I=H=O=512) + FC, bf16 MFMA compute.
//
// Round 5: round-2 structure (16 WG x 256 thr, VGPR ~216, weights in regs),
// sync primitive swapped: store-only parallel flags instead of 32-way
// atomic-RMW fan-in on a single LLC line.
//   producer: h stores (sc0 sc1) -> vmcnt(0) -> __syncthreads -> tid0 STORES
//             flags[wg]=s+1 (sc0 sc1).
//   consumer: tight-poll flags[l&15] (16 words, one 64B line), __all(v>=s).
// Skew <= 1 step; y rows per-timestep distinct => no parity buffers needed.
//
// Wave w (0..3): dir=w>>1, p=w&1; hidden slice j0=wg*32+p*16. W_hh fragments
// (3 gates x 16 kc x 8 bf16 = 192 VGPR/lane) persist in registers all 512
// steps; h carried in f32 regs (same lane owns same (b,j) forever).

typedef unsigned short u16;
typedef __attribute__((ext_vector_type(8))) short bf16x8;
typedef __attribute__((ext_vector_type(4))) float f32x4;

__device__ __forceinline__ u16 f2bf(float f) {
  unsigned u = __float_as_uint(f);
  u += 0x7fffu + ((u >> 16) & 1u);
  return (u16)(u >> 16);
}
__device__ __forceinline__ float bf2f(u16 v) {
  return __uint_as_float((unsigned)v << 16);
}

template<int AUX>
__device__ __forceinline__ void gl_lds16(const void* g, void* l) {
  __builtin_amdgcn_global_load_lds((const __attribute__((address_space(1))) void*)g,
                                   (__attribute__((address_space(3))) void*)l, 16, 0, AUX);
}

__device__ __forceinline__ void st_bf16_cc(u16* p, u16 v) {
  unsigned vv = v;
  asm volatile("global_store_short %0, %1, off sc0 sc1" :: "v"(p), "v"(vv) : "memory");
}
__device__ __forceinline__ void st_u32_cc(unsigned* p, unsigned v) {
  asm volatile("global_store_dword %0, %1, off sc0 sc1" :: "v"(p), "v"(v) : "memory");
}

// ---------------- utility kernels ----------------

__global__ void k_zero(unsigned* p, int n) {
  int i = blockIdx.x * blockDim.x + threadIdx.x;
  if (i < n) p[i] = 0u;
}

__global__ void k_cvt(const float* __restrict__ s, u16* __restrict__ d, int n) {
  int i = (blockIdx.x * blockDim.x + threadIdx.x) * 4;
  if (i < n) {
    float4 v = *(const float4*)(s + i);
    unsigned a = (unsigned)f2bf(v.x) | ((unsigned)f2bf(v.y) << 16);
    unsigned b = (unsigned)f2bf(v.z) | ((unsigned)f2bf(v.w) << 16);
    uint2 o; o.x = a; o.y = b;
    *(uint2*)(d + i) = o;
  }
}

__global__ void k_copyf(const float* __restrict__ s, float* __restrict__ d, int n) {
  int i = blockIdx.x * blockDim.x + threadIdx.x;
  if (i < n) d[i] = s[i];
}

// ------- tiled bf16 MFMA GEMM:  C[M,N] = A[M,K] * B[N,K]^T + bias -------

template<bool BF16OUT>
__global__ __launch_bounds__(256) void k_gemm(
    const u16* __restrict__ A, const u16* __restrict__ B,
    const float* __restrict__ bias, void* __restrict__ Cv,
    int N, int K)
{
  __shared__ u16 As[128 * 32];
  __shared__ u16 Bs[128 * 32];
  const int tid = threadIdx.x;
  const int w = tid >> 6, l = tid & 63;
  const int bm = blockIdx.x, bn = blockIdx.y;
  const int lj = l & 15, lk = l >> 4;
  const int wm = (w & 1) * 64, wn = (w >> 1) * 64;
  const int srow = l >> 2, scol = (l & 3) * 8;
  f32x4 acc[4][4] = {};
  const u16* Ab = A + (size_t)bm * 128 * K;
  const u16* Bb = B + (size_t)bn * 128 * K;

  for (int kt = 0; kt < K; kt += 32) {
#pragma unroll
    for (int i = 0; i < 2; ++i) {
      int r0 = i * 64 + w * 16;
      gl_lds16<0>(Ab + (size_t)(r0 + srow) * K + kt + scol, &As[r0 * 32]);
      gl_lds16<0>(Bb + (size_t)(r0 + srow) * K + kt + scol, &Bs[r0 * 32]);
    }
    __syncthreads();
    bf16x8 af[4], bf[4];
#pragma unroll
    for (int i = 0; i < 4; ++i) af[i] = *(const bf16x8*)&As[(wm + i * 16 + lj) * 32 + lk * 8];
#pragma unroll
    for (int j = 0; j < 4; ++j) bf[j] = *(const bf16x8*)&Bs[(wn + j * 16 + lj) * 32 + lk * 8];
#pragma unroll
    for (int i = 0; i < 4; ++i)
#pragma unroll
      for (int j = 0; j < 4; ++j)
        acc[i][j] = __builtin_amdgcn_mfma_f32_16x16x32_bf16(af[i], bf[j], acc[i][j], 0, 0, 0);
    __syncthreads();
  }

#pragma unroll
  for (int i = 0; i < 4; ++i)
#pragma unroll
    for (int j = 0; j < 4; ++j) {
      int col = bn * 128 + wn + j * 16 + lj;
      float bv = bias[col];
#pragma unroll
      for (int r2 = 0; r2 < 4; ++r2) {
        int row = bm * 128 + wm + i * 16 + lk * 4 + r2;
        float v = acc[i][j][r2] + bv;
        if (BF16OUT) ((u16*)Cv)[(size_t)row * N + col] = f2bf(v);
        else         ((float*)Cv)[(size_t)row * N + col] = v;
      }
    }
}

// ---------------- persistent GRU layer (both directions) ----------------

#define LSTR 536  // padded LDS row stride in bf16 elems (1072 B, 16B-aligned)

__global__ __launch_bounds__(256, 1) void k_gru(
    const u16*  __restrict__ gi,      // [512*32][3072] bf16; fwd 0:1536, bwd 1536:3072
    const float* __restrict__ whhf,   // [1536][512]
    const float* __restrict__ whhb,
    const float* __restrict__ bhhf,   // [1536]
    const float* __restrict__ bhhb,
    const float* __restrict__ h0,     // this layer: [2][32][512] f32
    const u16*  __restrict__ hinit,   // this layer: [2][32][512] bf16
    u16* __restrict__ y,              // [512][32][1024] bf16 (exchange + next layer)
    float* __restrict__ hn,           // this layer: [2][32][512] f32 (d_out)
    unsigned* __restrict__ flags)     // this layer: [16] tag words (=s+1 after step s)
{
  __shared__ u16 hl[2][32 * LSTR];    // 68.6 KB
  const int tid = threadIdx.x, wg = blockIdx.x;
  const int w = tid >> 6, l = tid & 63;
  const int dir = w >> 1, p = w & 1;
  const int j0 = wg * 32 + p * 16;
  const int lj = l & 15, lk = l >> 4;
  const float* whh = dir ? whhb : whhf;
  const float* bhh = dir ? bhhb : bhhf;

  // persistent W_hh fragments: [gate r/z/n][k-chunk]
  bf16x8 bfr[3][16];
#pragma unroll
  for (int g = 0; g < 3; ++g) {
    const float* wr = whh + (size_t)(g * 512 + j0 + lj) * 512;
#pragma unroll
    for (int kc = 0; kc < 16; ++kc) {
      const float* s4 = wr + kc * 32 + lk * 8;
      float4 a = *(const float4*)s4;
      float4 b = *(const float4*)(s4 + 4);
      bf16x8 v;
      v[0] = (short)f2bf(a.x); v[1] = (short)f2bf(a.y); v[2] = (short)f2bf(a.z); v[3] = (short)f2bf(a.w);
      v[4] = (short)f2bf(b.x); v[5] = (short)f2bf(b.y); v[6] = (short)f2bf(b.z); v[7] = (short)f2bf(b.w);
      bfr[g][kc] = v;
    }
  }
  float bb[3];
#pragma unroll
  for (int g = 0; g < 3; ++g) bb[g] = bhh[g * 512 + j0 + lj];

  float hreg[2][4];
#pragma unroll
  for (int mt = 0; mt < 2; ++mt)
#pragma unroll
    for (int i = 0; i < 4; ++i)
      hreg[mt][i] = h0[((size_t)dir * 32 + (mt * 16 + lk * 4 + i)) * 512 + j0 + lj];

  for (int s = 0; s < 512; ++s) {
    const int tq = dir ? (511 - s) : s;

    // prefetch input-gate values (plain loads; in flight during the flag wait)
    float gg[2][4][3];
#pragma unroll
    for (int mt = 0; mt < 2; ++mt)
#pragma unroll
      for (int i = 0; i < 4; ++i) {
        int b = mt * 16 + lk * 4 + i;
        const u16* gp = gi + ((size_t)tq * 32 + b) * 3072 + dir * 1536 + j0 + lj;
        gg[mt][i][0] = bf2f(gp[0]);
        gg[mt][i][1] = bf2f(gp[512]);
        gg[mt][i][2] = bf2f(gp[1024]);
      }

    if (s > 0) {
      const unsigned ss = (unsigned)s;
      unsigned cap = 0;
      for (;;) {
        unsigned v = __hip_atomic_load(&flags[l & 15], __ATOMIC_RELAXED,
                                       __HIP_MEMORY_SCOPE_AGENT);
        if (__all((int)(v >= ss))) break;
        if (++cap > (1u << 20)) break;  // safety: terminates, never hangs
      }
    }

    // stage h_prev of my dir into LDS: 2 waves/dir x 16 rows each (1 KB/row)
    {
      const u16* src; int rstride, cbase;
      if (s == 0) { src = hinit + (size_t)dir * 32 * 512; rstride = 512; cbase = 0; }
      else { int tp = dir ? (tq + 1) : (tq - 1); src = y + (size_t)tp * 32 * 1024; rstride = 1024; cbase = dir * 512; }
#pragma unroll
      for (int r = 0; r < 16; ++r) {
        int row = p * 16 + r;
        gl_lds16<17>(src + (size_t)row * rstride + cbase + l * 8, &hl[dir][row * LSTR]);
      }
    }
    __syncthreads();                      // gl_lds drained, LDS visible

    f32x4 acc[2][3];
#pragma unroll
    for (int mt = 0; mt < 2; ++mt)
#pragma unroll
      for (int g = 0; g < 3; ++g)
        acc[mt][g] = (f32x4){bb[g], bb[g], bb[g], bb[g]};

#pragma unroll
    for (int kc = 0; kc < 16; ++kc) {
      bf16x8 a0 = *(const bf16x8*)&hl[dir][lj * LSTR + kc * 32 + lk * 8];
      bf16x8 a1 = *(const bf16x8*)&hl[dir][(16 + lj) * LSTR + kc * 32 + lk * 8];
#pragma unroll
      for (int g = 0; g < 3; ++g) {
        acc[0][g] = __builtin_amdgcn_mfma_f32_16x16x32_bf16(a0, bfr[g][kc], acc[0][g], 0, 0, 0);
        acc[1][g] = __builtin_amdgcn_mfma_f32_16x16x32_bf16(a1, bfr[g][kc], acc[1][g], 0, 0, 0);
      }
    }
    __syncthreads();                      // protect LDS before next step's staging

    // epilogue: gates + h update + coherent y store
#pragma unroll
    for (int mt = 0; mt < 2; ++mt)
#pragma unroll
      for (int i = 0; i < 4; ++i) {
        int b = mt * 16 + lk * 4 + i;
        float r = 1.f / (1.f + __expf(-(gg[mt][i][0] + acc[mt][0][i])));
        float z = 1.f / (1.f + __expf(-(gg[mt][i][1] + acc[mt][1][i])));
        float nx = gg[mt][i][2] + r * acc[mt][2][i];
        float n = 1.f - 2.f / (1.f + __expf(2.f * nx));
        float h = (1.f - z) * n + z * hreg[mt][i];
        hreg[mt][i] = h;
        st_bf16_cc(y + ((size_t)tq * 32 + b) * 1024 + dir * 512 + j0 + lj, f2bf(h));
        if (s == 511) hn[((size_t)dir * 32 + b) * 512 + j0 + lj] = h;
      }

    asm volatile("s_waitcnt vmcnt(0)" ::: "memory");  // my h stores at LLC
    __syncthreads();                      // all 4 waves drained
    if (tid == 0) st_u32_cc(&flags[wg], (unsigned)(s + 1));  // parallel publish
  }
}

// ---------------- host ----------------

extern "C" void kernel_launch(void* const* d_in, const int* in_sizes, int n_in,
                              void* d_out, int out_size, void* d_ws, size_t ws_size,
                              hipStream_t stream)
{
  const float* x     = (const float*)d_in[0];
  const float* h     = (const float*)d_in[1];
  const float* wih0f = (const float*)d_in[2];
  const float* whh0f = (const float*)d_in[3];
  const float* bih0f = (const float*)d_in[4];
  const float* bhh0f = (const float*)d_in[5];
  const float* wih0b = (const float*)d_in[6];
  const float* whh0b = (const float*)d_in[7];
  const float* bih0b = (const float*)d_in[8];
  const float* bhh0b = (const float*)d_in[9];
  const float* wih1f = (const float*)d_in[10];
  const float* whh1f = (const float*)d_in[11];
  const float* bih1f = (const float*)d_in[12];
  const float* bhh1f = (const float*)d_in[13];
  const float* wih1b = (const float*)d_in[14];
  const float* whh1b = (const float*)d_in[15];
  const float* bih1b = (const float*)d_in[16];
  const float* bhh1b = (const float*)d_in[17];
  const float* fcw   = (const float*)d_in[18];
  const float* fcb   = (const float*)d_in[19];
  (void)in_sizes; (void)n_in; (void)out_size;

  char* ws = (char*)d_ws;
  size_t off = 0;
  auto alloc = [&](size_t bytes) { void* p = ws + off; off += (bytes + 255) & ~(size_t)255; return p; };
  u16*      gi    = (u16*)     alloc(16384ull * 3072 * 2);   // 100.7 MB
  u16*      y0    = (u16*)     alloc(16384ull * 1024 * 2);   // 33.6 MB
  char*     y1r   = (char*)    alloc(16384ull * 1024 * 2);   // 33.6 MB (aliased below)
  u16*      Wfc   = (u16*)     alloc(512ull * 1024 * 2);
  u16*      hinit = (u16*)     alloc(4ull * 32 * 512 * 2);
  float*    bias0 = (float*)   alloc(3072 * 4);
  float*    bias1 = (float*)   alloc(3072 * 4);
  unsigned* flags = (unsigned*)alloc(32 * 4);                // 16 per layer
  size_t need = off;

  if (ws_size < need) {  // diagnosable failure instead of a page fault
    hipMemsetAsync(d_out, 0, (size_t)out_size * sizeof(float), stream);
    return;
  }

  // xb / Wih0 / Wih1 die after GEMM1; y1 written only after that -> alias.
  u16* y1   = (u16*)y1r;
  u16* xb   = (u16*)y1r;
  u16* Wih0 = (u16*)(y1r + 16777216);
  u16* Wih1 = (u16*)(y1r + 16777216 + 3145728);

  float* out = (float*)d_out;
  float* hn  = out + 512ull * 32 * 512;

  k_zero<<<1, 64, 0, stream>>>(flags, 32);
  auto cvt = [&](const float* s, u16* d, int n) {
    k_cvt<<<dim3((n / 4 + 255) / 256), 256, 0, stream>>>(s, d, n);
  };
  cvt(x, xb, 16384 * 512);
  cvt(wih0f, Wih0, 1536 * 512);
  cvt(wih0b, Wih0 + 1536 * 512, 1536 * 512);
  cvt(wih1f, Wih1, 1536 * 1024);
  cvt(wih1b, Wih1 + 1536 * 1024, 1536 * 1024);
  cvt(fcw, Wfc, 512 * 1024);
  cvt(h, hinit, 4 * 32 * 512);
  k_copyf<<<6, 256, 0, stream>>>(bih0f, bias0, 1536);
  k_copyf<<<6, 256, 0, stream>>>(bih0b, bias0 + 1536, 1536);
  k_copyf<<<6, 256, 0, stream>>>(bih1f, bias1, 1536);
  k_copyf<<<6, 256, 0, stream>>>(bih1b, bias1 + 1536, 1536);

  // layer 0
  k_gemm<true><<<dim3(128, 24), 256, 0, stream>>>(xb, Wih0, bias0, gi, 3072, 512);
  k_gru<<<16, 256, 0, stream>>>(gi, whh0f, whh0b, bhh0f, bhh0b,
                                h, hinit, y0, hn, flags);
  // layer 1
  k_gemm<true><<<dim3(128, 24), 256, 0, stream>>>(y0, Wih1, bias1, gi, 3072, 1024);
  k_gru<<<16, 256, 0, stream>>>(gi, whh1f, whh1b, bhh1f, bhh1b,
                                h + 2 * 32 * 512, hinit + 2 * 32 * 512,
                                y1, hn + 2ull * 32 * 512, flags + 16);
  // FC
  k_gemm<false><<<dim3(128, 4), 256, 0, stream>>>(y1, Wfc, fcb, out, 512, 1024);
}